// Round 18
// baseline (60.749 us; speedup 1.0000x reference)
//
#include <hip/hip_runtime.h>

// 4 kernels, 3 boundaries:
//  k_dot (500 blk): V = h @ W_top (HBM floor ~10.5us), MA = bitmask(g); CNT=0
//  k_row (125 blk): SH = relu(g.V + b_top) -> out[0:500]
//  k_row (125 blk): Z  = relu((g.SH)*Wp0 + bp0)  (sigmoid monotone)
//  k_rhf (32 blk x 1024, wave/orig-row): rank_i -> IDXA[rank]=i, HSo;
//        selected rows compute un2 (2-hop nbhd in full g), CPP[i] = ~un2 &
//        mask500 (~1-3 bits). Cross-block outputs via RELAXED agent-scope
//        atomics (LLC-coherent; validated bit-exact in the R13 structure);
//        __syncthreads drains vmcnt -> stores LLC-visible before the
//        arrive-add. LAST block (atomicAdd(CNT)==31) runs the fin body
//        in-place: SEL, RSUM = 400 - |SEL ∩ CPP|, m0 + z1 (total - complement
//        walks), rank1 (packed pairs), hop1 (intersect, early exit), scalar
//        cascade (complete-graph fast path; verified general fallback).
// ws (u32): V@0, SHg@512, Zg@1024, IDXA@1536, HSo@2048, CNT@2592,
// CPP@2624(8000), MA@10624(8000)

#define MS 16
struct P4 { const float* p[4]; };

// relaxed agent-scope (LLC-coherent) helpers — bypass non-coherent per-XCD L2
__device__ __forceinline__ float ald(const float* p) {
    return __hip_atomic_load(p, __ATOMIC_RELAXED, __HIP_MEMORY_SCOPE_AGENT);
}
__device__ __forceinline__ void ast(float* p, float v) {
    __hip_atomic_store(p, v, __ATOMIC_RELAXED, __HIP_MEMORY_SCOPE_AGENT);
}
__device__ __forceinline__ unsigned aldu(const unsigned* p) {
    return __hip_atomic_load(p, __ATOMIC_RELAXED, __HIP_MEMORY_SCOPE_AGENT);
}
__device__ __forceinline__ void astu(unsigned* p, unsigned v) {
    __hip_atomic_store(p, v, __ATOMIC_RELAXED, __HIP_MEMORY_SCOPE_AGENT);
}
__device__ __forceinline__ int aldi(const int* p) {
    return __hip_atomic_load(p, __ATOMIC_RELAXED, __HIP_MEMORY_SCOPE_AGENT);
}
__device__ __forceinline__ void asti(int* p, int v) {
    __hip_atomic_store(p, v, __ATOMIC_RELAXED, __HIP_MEMORY_SCOPE_AGENT);
}

__device__ __forceinline__ float bitselF(unsigned m, int k, float v) {
    int s = ((int)(m << (31 - k))) >> 31;
    return __int_as_float(s & __float_as_int(v));
}
__device__ __forceinline__ float fbfly(float v) {
#pragma unroll
    for (int o = 32; o; o >>= 1) v += __shfl_xor(v, o);
    return v;
}
__device__ __forceinline__ int ibfly(int v) {
#pragma unroll
    for (int o = 32; o; o >>= 1) v += __shfl_xor(v, o);
    return v;
}
__device__ __forceinline__ float sigm(float x) { return 1.f / (1.f + expf(-x)); }

// sparse bit-walk over a 16-word LDS row (rows have ~1-3 bits set)
__device__ __forceinline__ float pwalk16(const unsigned* __restrict__ row,
                                         const float* __restrict__ val) {
    float a = 0.f;
#pragma unroll
    for (int w = 0; w < 16; ++w) {
        unsigned m = row[w];
        while (m) {
            int b = __ffs((int)m) - 1;
            m &= m - 1;
            a += val[(w << 5) + b];
        }
    }
    return a;
}

// wave-cooperative stable rank over padded-512 LDS array (pads = -1)
__device__ __forceinline__ int wrank(const float* __restrict__ sc, float my,
                                     int r, int lane) {
    int cnt = 0;
#pragma unroll
    for (int q = 0; q < 8; ++q) {
        int j = lane + 64 * q;
        float s = sc[j];
        cnt += (s > my) || (s == my && j < r);
    }
    return ibfly(cnt);
}

// K1: V[row] = dot(h[row,:], W_top); MA[row] = bitmask(g row); CNT=0.
__global__ __launch_bounds__(1024) void k_dot(const float* __restrict__ h,
        const float* __restrict__ Wt, const float* __restrict__ g,
        float* __restrict__ V, unsigned* __restrict__ MA,
        unsigned* __restrict__ CNT) {
    int row = blockIdx.x, t = threadIdx.x;
    if (row == 0 && t == 0) astu(CNT, 0u);
    const float4* h4 = (const float4*)(h + (size_t)row * 32768);
    const float4* w4 = (const float4*)Wt;
    float acc = 0.f;
#pragma unroll
    for (int j = 0; j < 8; ++j) {
        float4 a = h4[t + 1024 * j], b = w4[t + 1024 * j];
        acc = fmaf(a.x, b.x, fmaf(a.y, b.y, fmaf(a.z, b.z, fmaf(a.w, b.w, acc))));
    }
    acc = fbfly(acc);
    __shared__ float red[16];
    if ((t & 63) == 0) red[t >> 6] = acc;
    __syncthreads();
    if (t == 0) {
        float s = 0.f;
        for (int i = 0; i < 16; ++i) s += red[i];
        V[row] = s;
    }
    if (t < 512) {
        float gv = (t < 500) ? g[row * 500 + t] : 0.f;
        unsigned long long bal = __ballot(gv != 0.f);
        if ((t & 63) == 0) {
            int w = t >> 6;
            MA[row * MS + 2 * w] = (unsigned)bal;
            MA[row * MS + 2 * w + 1] = (unsigned)(bal >> 32);
        }
    }
}

// K2/K3: wave-per-row masked matvec on sparse g.
// mode 0: y = relu(acc + c0), also out[r]. mode 1: y = relu(acc*c0 + c1).
__global__ __launch_bounds__(256) void k_row(const unsigned* __restrict__ MA,
        const float* __restrict__ x, const float* __restrict__ c0,
        const float* __restrict__ c1, float* __restrict__ y,
        float* __restrict__ out, int mode) {
    __shared__ float sv[512];
    int t = threadIdx.x;
    sv[t] = (t < 500) ? x[t] : 0.f;
    int t2 = t + 256;
    sv[t2] = (t2 < 500) ? x[t2] : 0.f;
    __syncthreads();
    int wid = t >> 6, lane = t & 63;
    int r = blockIdx.x * 4 + wid;
    float acc = 0.f;
#pragma unroll
    for (int j = 0; j < 8; ++j) {
        unsigned m = MA[r * MS + 2 * j + (lane >> 5)];
        acc += bitselF(m, lane & 31, sv[64 * j + lane]);
    }
    acc = fbfly(acc);
    if (lane == 0) {
        if (mode == 0) {
            float hv = fmaxf(acc + c0[0], 0.f);
            out[r] = hv;
            y[r] = hv;
        } else {
            y[r] = fmaxf(acc * c0[0] + c1[0], 0.f);
        }
    }
}

// K4: rank + un2 (wave/orig-row, zero redundancy); last-done block runs fin.
__global__ __launch_bounds__(1024) void k_rhf(const unsigned* __restrict__ MA,
        const float* __restrict__ SHg, const float* __restrict__ Zg,
        int* __restrict__ IDXA, float* __restrict__ HSo,
        unsigned* __restrict__ CPP, unsigned* __restrict__ CNT,
        P4 Wp, P4 bp, P4 Wd, P4 bd, float* __restrict__ out) {
    __shared__ __align__(16) unsigned sMA[8000];  // reused as sCP in fin
    __shared__ float sz[512];
    __shared__ float szC[512], svC[512], s2C[512];
    __shared__ float svO[512], s2O[512], shvO[512], sHSo[512], srsO[512];
    __shared__ int sIDXp[2][512];
    __shared__ unsigned sSELp[2][16];
    __shared__ float sS[8];
    __shared__ float stot0, stot1, stotS;
    __shared__ int sFlag, sLast;
    int t = threadIdx.x, wid = t >> 6, lane = t & 63;
    for (int q = t; q < 2000; q += 1024)
        ((uint4*)sMA)[q] = ((const uint4*)MA)[q];
    if (t < 512) sz[t] = (t < 500) ? Zg[t] : -1.f;
    __syncthreads();
    // ---- row phase: wave per orig row ----
    int i = blockIdx.x * 16 + wid;  // 0..511
    if (i < 500) {
        float my = sz[i];
        int rank = wrank(sz, my, i, lane);
        if (rank < 400) {
            if (lane == 0) {
                asti(&IDXA[rank], i);
                ast(&HSo[i], SHg[i] * sigm(my));
            }
            int part = lane >> 4, w = lane & 15;
            unsigned acc = 0;
            for (int k = part; k < 500; k += 4) {
                unsigned sel = (sMA[i * MS + (k >> 5)] >> (k & 31)) & 1u;
                acc |= sMA[k * MS + w] & (0u - sel);
            }
            acc |= (unsigned)__shfl_xor((int)acc, 16);
            acc |= (unsigned)__shfl_xor((int)acc, 32);
            if (lane < 16) {
                unsigned m500 = (lane < 15) ? 0xffffffffu : 0xfffffu;
                astu(&CPP[i * MS + lane], ~acc & m500);
            }
        }
    }
    __syncthreads();  // drains vmcnt: all atomic stores LLC-visible
    if (t == 0) {
        unsigned old = __hip_atomic_fetch_add(CNT, 1u, __ATOMIC_RELAXED,
                                              __HIP_MEMORY_SCOPE_AGENT);
        sLast = (old == 31u);
    }
    __syncthreads();
    if (!sLast) return;

    // ======== fin (last block only; R17-verified body, atomic loads) ========
    unsigned* sCP = sMA;  // row phase done; reuse LDS
    for (int q = t; q < 8000; q += 1024) sCP[q] = aldu(&CPP[q]);
    if (t < 512) {
        sIDXp[0][t] = (t < 400) ? aldi(&IDXA[t]) : 0;
        svO[t] = 0.f;
        s2O[t] = 0.f;
        svC[t] = 0.f;
        srsO[t] = 1.f;
    }
    if (t < 16) {
        sSELp[0][t] = 0u;
        sSELp[1][t] = 0u;
    }
    if (t == 0) sFlag = 0;
    __syncthreads();
    if (t < 400) {
        int ii = sIDXp[0][t];
        atomicOr(&sSELp[0][ii >> 5], 1u << (ii & 31));
    }
    __syncthreads();
    // RSUM = 400 - |SEL ∩ CPP_i|; SU
    if (t < 400) {
        int ii = sIDXp[0][t];
        int cnt = 0;
#pragma unroll
        for (int w = 0; w < 16; ++w) {
            unsigned m = sCP[ii * MS + w];
            unsigned sw = sSELp[0][w];
            while (m) {
                int b = __ffs((int)m) - 1;
                m &= m - 1;
                cnt += (sw >> b) & 1;
            }
        }
        float rs = (float)(400 - cnt);
        srsO[ii] = rs;
        float su = ald(&HSo[ii]) * Wd.p[0][t] / rs;
        svC[t] = su;
        svO[ii] = su;
    }
    __syncthreads();
    if (t < 64) {
        float p = 0.f;
#pragma unroll
        for (int j = 0; j < 8; ++j) p += svC[t * 8 + j];
        p = fbfly(p);
        if (t == 0) stot0 = p;
    }
    __syncthreads();
    // m0 -> out[500:900]
    int i0 = 0;
    if (t < 400) {
        i0 = sIDXp[0][t];
        float corr = pwalk16(sCP + i0 * MS, svO);
        float h1 = fmaxf(stot0 - corr + bd.p[0][0], 0.f);
        out[500 + t] = h1;
        shvO[i0] = h1;
        float s2 = h1 / srsO[i0];
        s2C[t] = s2;
        s2O[i0] = s2;
    } else if (t < 512) {
        s2C[t] = 0.f;
    }
    __syncthreads();
    if (t < 64) {
        float p = 0.f;
#pragma unroll
        for (int j = 0; j < 8; ++j) p += s2C[t * 8 + j];
        p = fbfly(p);
        if (t == 0) stot1 = p;
    }
    __syncthreads();
    // z1
    if (t < 400) {
        float c2 = pwalk16(sCP + i0 * MS, s2O);
        szC[t] = fmaxf((stot1 - c2) * Wp.p[1][0] + bp.p[1][0], 0.f);
    } else if (t < 512) {
        szC[t] = -1.f;
    }
    __syncthreads();
    // rank1: top-300 of 400, packed pairs
    for (int r0 = wid * 2; r0 < 400; r0 += 32) {
        int r1 = r0 + 1;
        float my0 = szC[r0], my1 = szC[r1];
        int cnt = 0;
#pragma unroll
        for (int q = 0; q < 8; ++q) {
            int j = lane + 64 * q;
            float s = szC[j];
            cnt += (s > my0) || (s == my0 && j < r0);
            cnt += ((s > my1) || (s == my1 && j < r1)) << 16;
        }
        cnt = ibfly(cnt);
        if (lane == 0) {
            int c0 = cnt & 0xffff, c1 = cnt >> 16;
            if (c0 < 300) {
                int io = sIDXp[0][r0];
                sIDXp[1][c0] = io;
                sHSo[io] = shvO[io] * sigm(my0);
                atomicOr(&sSELp[1][io >> 5], 1u << (io & 31));
            }
            if (c1 < 300) {
                int io = sIDXp[0][r1];
                sIDXp[1][c1] = io;
                sHSo[io] = shvO[io] * sigm(my1);
                atomicOr(&sSELp[1][io >> 5], 1u << (io & 31));
            }
        }
    }
    __syncthreads();
    // hop1: P = SEL2 ∩ CPP[j1] ∩ ..., early exit
    unsigned P[16];
    int inew = 0, pc = 0;
    float su_ = 0.f;
    if (t < 300) {
        inew = sIDXp[1][t];
#pragma unroll
        for (int w = 0; w < 16; ++w) P[w] = sSELp[1][w];
        bool alive = true;
        for (int w2 = 0; w2 < 16 && alive; ++w2) {
            unsigned nb = sSELp[0][w2] & ~sCP[inew * MS + w2];
            while (nb) {
                int b = __ffs((int)nb) - 1;
                nb &= nb - 1;
                const unsigned* cj = sCP + (w2 * 32 + b) * MS;
                unsigned orr = 0;
#pragma unroll
                for (int w = 0; w < 16; ++w) {
                    P[w] &= cj[w];
                    orr |= P[w];
                }
                if (!orr) { alive = false; break; }
            }
        }
#pragma unroll
        for (int w = 0; w < 16; ++w) pc += __popc(P[w]);
        if (pc > 0) atomicOr(&sFlag, 1);
        float rs = (float)(300 - pc);
        su_ = sHSo[inew] * Wd.p[1][t] / rs;
    }
    __syncthreads();
    if (t < 300) {
#pragma unroll
        for (int w = 0; w < 16; ++w) sCP[inew * MS + w] = P[w];
        srsO[inew] = (float)(300 - pc);
        svC[t] = su_;
        svO[inew] = su_;
    } else if (t < 512) {
        svC[t] = 0.f;
    }
    __syncthreads();
    if (sFlag == 0) {
        // ---- scalar fast path: layers 1-3 graphs are complete ----
        if (t < 64) {
            float p = 0.f;
#pragma unroll
            for (int j = 0; j < 8; ++j) p += svC[t * 8 + j];
            p = fbfly(p);
            if (t == 0) {
                float h2 = fmaxf(p + bd.p[1][0], 0.f);
                float z2 = fmaxf(h2 * Wp.p[2][0] + bp.p[2][0], 0.f);
                sS[0] = h2;
                sS[1] = h2 * sigm(z2);
            }
        }
        __syncthreads();
        float HS2 = sS[1];
        if (t < 512) s2C[t] = (t < 200) ? HS2 * Wd.p[2][t] / 200.f : 0.f;
        __syncthreads();
        if (t < 64) {
            float p = 0.f;
#pragma unroll
            for (int j = 0; j < 8; ++j) p += s2C[t * 8 + j];
            p = fbfly(p);
            if (t == 0) {
                float h3 = fmaxf(p + bd.p[2][0], 0.f);
                float z3 = fmaxf(h3 * Wp.p[3][0] + bp.p[3][0], 0.f);
                sS[2] = h3;
                sS[3] = h3 * sigm(z3);
            }
        }
        __syncthreads();
        float HS3 = sS[3];
        if (t < 512) s2C[t] = (t < 100) ? HS3 * Wd.p[3][t] / 100.f : 0.f;
        __syncthreads();
        if (t < 64) {
            float p = 0.f;
#pragma unroll
            for (int j = 0; j < 8; ++j) p += s2C[t * 8 + j];
            p = fbfly(p);
            if (t == 0) sS[4] = fmaxf(p + bd.p[3][0], 0.f);
        }
        __syncthreads();
        if (t < 300) out[900 + t] = sS[0];
        else if (t < 500) out[1200 + (t - 300)] = sS[2];
        else if (t < 600) out[1400 + (t - 500)] = sS[4];
        return;
    }
    // ---- general fallback (correct; not expected to execute) ----
    const int kks[3] = {300, 200, 100};
    const int kns[3] = {200, 100, 0};
    const int offs[3] = {900, 1200, 1400};
    for (int l = 1; l <= 3; ++l) {
        const int kk = kks[l - 1], knext = kns[l - 1], off = offs[l - 1];
        const int cur = l & 1, nxt = cur ^ 1;
        if (t < 64) {
            float p = 0.f;
#pragma unroll
            for (int j = 0; j < 8; ++j) p += svC[t * 8 + j];
            p = fbfly(p);
            if (t == 0) stotS = p;
        }
        __syncthreads();
        int i_ = 0;
        if (t < kk) {
            i_ = sIDXp[cur][t];
            float corr = pwalk16(sCP + i_ * MS, svO);
            float hv = fmaxf(stotS - corr + bd.p[l][0], 0.f);
            out[off + t] = hv;
            shvO[i_] = hv;
            float s2 = hv / srsO[i_];
            s2C[t] = s2;
            s2O[i_] = s2;
        } else if (t < 512) {
            s2C[t] = 0.f;
        }
        if (l == 3) break;
        __syncthreads();
        if (t < 64) {
            float p = 0.f;
#pragma unroll
            for (int j = 0; j < 8; ++j) p += s2C[t * 8 + j];
            p = fbfly(p);
            if (t == 0) stotS = p;
        }
        if (t < 16) sSELp[nxt][t] = 0u;
        __syncthreads();
        float z_ = -1.f;
        if (t < kk) {
            float c2 = pwalk16(sCP + i_ * MS, s2O);
            z_ = fmaxf((stotS - c2) * Wp.p[l + 1][0] + bp.p[l + 1][0], 0.f);
        }
        if (t < 512) szC[t] = (t < kk) ? z_ : -1.f;
        __syncthreads();
        for (int r = wid; r < kk; r += 16) {
            float my = szC[r];
            int cnt = wrank(szC, my, r, lane);
            if (lane == 0 && cnt < knext) {
                int io = sIDXp[cur][r];
                sIDXp[nxt][cnt] = io;
                sHSo[io] = shvO[io] * sigm(my);
                atomicOr(&sSELp[nxt][io >> 5], 1u << (io & 31));
            }
        }
        __syncthreads();
        unsigned Q[16];
        int in2 = 0, pc2 = 0;
        float su2_ = 0.f;
        if (t < knext) {
            in2 = sIDXp[nxt][t];
#pragma unroll
            for (int w = 0; w < 16; ++w) Q[w] = sSELp[nxt][w];
            bool alive = true;
            for (int w2 = 0; w2 < 16 && alive; ++w2) {
                unsigned nb = sSELp[cur][w2] & ~sCP[in2 * MS + w2];
                while (nb) {
                    int b = __ffs((int)nb) - 1;
                    nb &= nb - 1;
                    const unsigned* cj = sCP + (w2 * 32 + b) * MS;
                    unsigned orr = 0;
#pragma unroll
                    for (int w = 0; w < 16; ++w) {
                        Q[w] &= cj[w];
                        orr |= Q[w];
                    }
                    if (!orr) { alive = false; break; }
                }
            }
#pragma unroll
            for (int w = 0; w < 16; ++w) pc2 += __popc(Q[w]);
            float rs = (float)(knext - pc2);
            su2_ = sHSo[in2] * Wd.p[l + 1][t] / rs;
        }
        __syncthreads();
        if (t < knext) {
#pragma unroll
            for (int w = 0; w < 16; ++w) sCP[in2 * MS + w] = Q[w];
            srsO[in2] = (float)(knext - pc2);
            svC[t] = su2_;
            svO[in2] = su2_;
        } else if (t < 512) {
            svC[t] = 0.f;
        }
        __syncthreads();
    }
}

extern "C" void kernel_launch(void* const* d_in, const int* in_sizes, int n_in,
                              void* d_out, int out_size, void* d_ws, size_t ws_size,
                              hipStream_t stream) {
    const float* g = (const float*)d_in[0];
    const float* h = (const float*)d_in[1];
    const float* W_top = (const float*)d_in[2];
    const float* b_top = (const float*)d_in[3];
    P4 Wp, bp, Wd, bd;
    for (int i = 0; i < 4; ++i) {
        Wp.p[i] = (const float*)d_in[4 + 4 * i];
        bp.p[i] = (const float*)d_in[5 + 4 * i];
        Wd.p[i] = (const float*)d_in[6 + 4 * i];
        bd.p[i] = (const float*)d_in[7 + 4 * i];
    }
    float* out = (float*)d_out;

    unsigned* wsu = (unsigned*)d_ws;
    float* V = (float*)(wsu + 0);
    float* SHg = (float*)(wsu + 512);
    float* Zg = (float*)(wsu + 1024);
    int* IDXA = (int*)(wsu + 1536);
    float* HSo = (float*)(wsu + 2048);
    unsigned* CNT = wsu + 2592;
    unsigned* CPP = wsu + 2624;
    unsigned* MA = wsu + 10624;

    k_dot<<<500, 1024, 0, stream>>>(h, W_top, g, V, MA, CNT);
    k_row<<<125, 256, 0, stream>>>(MA, V, b_top, nullptr, SHg, out, 0);
    k_row<<<125, 256, 0, stream>>>(MA, SHg, Wp.p[0], bp.p[0], Zg, nullptr, 1);
    k_rhf<<<32, 1024, 0, stream>>>(MA, SHg, Zg, IDXA, HSo, CPP, CNT,
                                   Wp, bp, Wd, bd, out);
}

// Round 19
// 56.093 us; speedup vs baseline: 1.0830x; 1.0830x over previous
//
#include <hip/hip_runtime.h>

// 5 kernels, 4 boundaries — measured best (R15: 55.6us, absmax 0).
//  k_dot (500 blk): V = h @ W_top (HBM floor ~10.5us), MA = bitmask(g)
//  k_row (125 blk): SH = relu(g.V + b_top) -> out[0:500]
//  k_row (125 blk): Z  = relu((g.SH)*Wp0 + bp0)  (sigmoid monotone)
//  k_rh  (125 blk, wave/orig-row): rank_i (1 wrank/wave) -> IDXA[rank]=i,
//        HSo[i]; selected rows also compute un2 (2-hop nbhd in full g) and
//        store CPP[i] = ~un2 & mask500 (~1-3 bits). SEL-projection deferred.
//  k_fin (1 blk x 1024): rebuild SEL from IDXA, CP = CPP & SEL, RSUM, SU,
//        m0 + z1 (total - complement walks) + rank1 (paired/packed wrank)
//        + hop1 (intersect complements, early exit) + scalar cascade
//        (complete-graph fast path; verified general fallback). out[500:1500].
// Structural plateau: total = k_dot HBM floor + 4 boundaries (~2-4us each) +
// ~30us single-CU sequential tail (rank1->hop1->cascade dependency chain).
// ws (u32): V@0, SHg@512, Zg@1024, IDXA@1536, HSo@2048, CPP@2560(8000),
// MA@10560(8000)

#define MS 16
struct P4 { const float* p[4]; };

__device__ __forceinline__ float bitselF(unsigned m, int k, float v) {
    int s = ((int)(m << (31 - k))) >> 31;
    return __int_as_float(s & __float_as_int(v));
}
__device__ __forceinline__ float fbfly(float v) {
#pragma unroll
    for (int o = 32; o; o >>= 1) v += __shfl_xor(v, o);
    return v;
}
__device__ __forceinline__ int ibfly(int v) {
#pragma unroll
    for (int o = 32; o; o >>= 1) v += __shfl_xor(v, o);
    return v;
}
__device__ __forceinline__ float sigm(float x) { return 1.f / (1.f + expf(-x)); }

// sparse bit-walk over a 16-word LDS row (rows have ~1-3 bits set)
__device__ __forceinline__ float pwalk16(const unsigned* __restrict__ row,
                                         const float* __restrict__ val) {
    float a = 0.f;
#pragma unroll
    for (int w = 0; w < 16; ++w) {
        unsigned m = row[w];
        while (m) {
            int b = __ffs((int)m) - 1;
            m &= m - 1;
            a += val[(w << 5) + b];
        }
    }
    return a;
}

// wave-cooperative stable rank over padded-512 LDS array (pads = -1)
__device__ __forceinline__ int wrank(const float* __restrict__ sc, float my,
                                     int r, int lane) {
    int cnt = 0;
#pragma unroll
    for (int q = 0; q < 8; ++q) {
        int j = lane + 64 * q;
        float s = sc[j];
        cnt += (s > my) || (s == my && j < r);
    }
    return ibfly(cnt);
}

// K1: V[row] = dot(h[row,:], W_top); MA[row] = bitmask(g row).
__global__ __launch_bounds__(1024) void k_dot(const float* __restrict__ h,
        const float* __restrict__ Wt, const float* __restrict__ g,
        float* __restrict__ V, unsigned* __restrict__ MA) {
    int row = blockIdx.x, t = threadIdx.x;
    const float4* h4 = (const float4*)(h + (size_t)row * 32768);
    const float4* w4 = (const float4*)Wt;
    float acc = 0.f;
#pragma unroll
    for (int j = 0; j < 8; ++j) {
        float4 a = h4[t + 1024 * j], b = w4[t + 1024 * j];
        acc = fmaf(a.x, b.x, fmaf(a.y, b.y, fmaf(a.z, b.z, fmaf(a.w, b.w, acc))));
    }
    acc = fbfly(acc);
    __shared__ float red[16];
    if ((t & 63) == 0) red[t >> 6] = acc;
    __syncthreads();
    if (t == 0) {
        float s = 0.f;
        for (int i = 0; i < 16; ++i) s += red[i];
        V[row] = s;
    }
    if (t < 512) {
        float gv = (t < 500) ? g[row * 500 + t] : 0.f;
        unsigned long long bal = __ballot(gv != 0.f);
        if ((t & 63) == 0) {
            int w = t >> 6;
            MA[row * MS + 2 * w] = (unsigned)bal;
            MA[row * MS + 2 * w + 1] = (unsigned)(bal >> 32);
        }
    }
}

// K2/K3: wave-per-row masked matvec on sparse g.
// mode 0: y = relu(acc + c0), also out[r]. mode 1: y = relu(acc*c0 + c1).
__global__ __launch_bounds__(256) void k_row(const unsigned* __restrict__ MA,
        const float* __restrict__ x, const float* __restrict__ c0,
        const float* __restrict__ c1, float* __restrict__ y,
        float* __restrict__ out, int mode) {
    __shared__ float sv[512];
    int t = threadIdx.x;
    sv[t] = (t < 500) ? x[t] : 0.f;
    int t2 = t + 256;
    sv[t2] = (t2 < 500) ? x[t2] : 0.f;
    __syncthreads();
    int wid = t >> 6, lane = t & 63;
    int r = blockIdx.x * 4 + wid;
    float acc = 0.f;
#pragma unroll
    for (int j = 0; j < 8; ++j) {
        unsigned m = MA[r * MS + 2 * j + (lane >> 5)];
        acc += bitselF(m, lane & 31, sv[64 * j + lane]);
    }
    acc = fbfly(acc);
    if (lane == 0) {
        if (mode == 0) {
            float hv = fmaxf(acc + c0[0], 0.f);
            out[r] = hv;
            y[r] = hv;
        } else {
            y[r] = fmaxf(acc * c0[0] + c1[0], 0.f);
        }
    }
}

// K4: rank + un2, wave per orig row (zero redundancy).
__global__ __launch_bounds__(256) void k_rh(const unsigned* __restrict__ MA,
        const float* __restrict__ SHg, const float* __restrict__ Zg,
        int* __restrict__ IDXA, float* __restrict__ HSo,
        unsigned* __restrict__ CPP) {
    __shared__ __align__(16) unsigned sMA[8000];
    __shared__ float sz[512];
    int t = threadIdx.x, wid = t >> 6, lane = t & 63;
    for (int q = t; q < 2000; q += 256)
        ((uint4*)sMA)[q] = ((const uint4*)MA)[q];
    if (t < 500) sz[t] = Zg[t];
    else if (t < 512) sz[t] = -1.f;
    int t2 = t + 256;
    if (t2 < 500) sz[t2] = Zg[t2];
    else if (t2 < 512) sz[t2] = -1.f;
    __syncthreads();
    int i = blockIdx.x * 4 + wid;
    float my = sz[i];
    int rank = wrank(sz, my, i, lane);
    if (rank >= 400) return;  // wave-uniform exit
    if (lane == 0) {
        IDXA[rank] = i;
        HSo[i] = SHg[i] * sigm(my);
    }
    // un2 = OR of g-rows over neighbors of i (dense column scan, 4-part)
    int part = lane >> 4, w = lane & 15;
    unsigned acc = 0;
    for (int k = part; k < 500; k += 4) {
        unsigned sel = (sMA[i * MS + (k >> 5)] >> (k & 31)) & 1u;
        acc |= sMA[k * MS + w] & (0u - sel);
    }
    acc |= (unsigned)__shfl_xor((int)acc, 16);
    acc |= (unsigned)__shfl_xor((int)acc, 32);
    if (lane < 16) {
        unsigned m500 = (lane < 15) ? 0xffffffffu : 0xfffffu;  // 500 bits
        CPP[i * MS + lane] = ~acc & m500;
    }
}

// K5: SEL-build + CP-project + m0 + z1 + rank1 + hop1 + cascade. 1 blk x 1024.
__global__ __launch_bounds__(1024) void k_fin(const int* __restrict__ IDXA,
        const unsigned* __restrict__ CPP, const float* __restrict__ HSo,
        P4 Wp, P4 bp, P4 Wd, P4 bd, float* __restrict__ out) {
    __shared__ __align__(16) unsigned sCP[8000];
    __shared__ float szC[512], svC[512], s2C[512];
    __shared__ float svO[512], s2O[512], shvO[512], sHSo[512], srsO[512];
    __shared__ int sIDXp[2][512];
    __shared__ unsigned sSELp[2][16];
    __shared__ float sS[8];
    __shared__ float stot0, stot1, stotS;
    __shared__ int sFlag;
    int t = threadIdx.x, wid = t >> 6, lane = t & 63;
    if (t < 512) sIDXp[0][t] = (t < 400) ? IDXA[t] : 0;
    if (t < 16) {
        sSELp[0][t] = 0u;
        sSELp[1][t] = 0u;
    }
    if (t == 0) sFlag = 0;
    __syncthreads();
    if (t < 400) {
        int i = sIDXp[0][t];
        atomicOr(&sSELp[0][i >> 5], 1u << (i & 31));
    }
    __syncthreads();
    // CP projection: sCP[i] = CPP[i] & SEL (selected rows only)
    for (int q = t; q < 6400; q += 1024) {
        int c = q >> 4, w = q & 15;
        int i = sIDXp[0][c];
        sCP[i * MS + w] = CPP[i * MS + w] & sSELp[0][w];
    }
    __syncthreads();
    // RSUM + SU (compact + orig)
    if (t < 400) {
        int i = sIDXp[0][t];
        int pc = 0;
#pragma unroll
        for (int w = 0; w < 16; ++w) pc += __popc(sCP[i * MS + w]);
        float rs = (float)(400 - pc);
        srsO[i] = rs;
        float su = HSo[i] * Wd.p[0][t] / rs;
        svC[t] = su;
        svO[i] = su;
    } else if (t < 512) {
        svC[t] = 0.f;
    }
    __syncthreads();
    // tot0
    if (t < 64) {
        float p = 0.f;
#pragma unroll
        for (int j = 0; j < 8; ++j) p += svC[t * 8 + j];
        p = fbfly(p);
        if (t == 0) stot0 = p;
    }
    __syncthreads();
    // m0: h1 = relu(tot0 - complement + bd0) -> out[500:900]
    int i0 = 0;
    if (t < 400) {
        i0 = sIDXp[0][t];
        float corr = pwalk16(sCP + i0 * MS, svO);
        float h1 = fmaxf(stot0 - corr + bd.p[0][0], 0.f);
        out[500 + t] = h1;
        shvO[i0] = h1;
        float s2 = h1 / srsO[i0];
        s2C[t] = s2;
        s2O[i0] = s2;
    } else if (t < 512) {
        s2C[t] = 0.f;
    }
    __syncthreads();
    // tot1
    if (t < 64) {
        float p = 0.f;
#pragma unroll
        for (int j = 0; j < 8; ++j) p += s2C[t * 8 + j];
        p = fbfly(p);
        if (t == 0) stot1 = p;
    }
    __syncthreads();
    // z1
    if (t < 400) {
        float c2 = pwalk16(sCP + i0 * MS, s2O);
        szC[t] = fmaxf((stot1 - c2) * Wp.p[1][0] + bp.p[1][0], 0.f);
    } else if (t < 512) {
        szC[t] = -1.f;
    }
    __syncthreads();
    // rank1: top-300 of 400, paired rows with packed counts
    for (int r0 = wid * 2; r0 < 400; r0 += 32) {
        int r1 = r0 + 1;
        float my0 = szC[r0], my1 = szC[r1];
        int cnt = 0;
#pragma unroll
        for (int q = 0; q < 8; ++q) {
            int j = lane + 64 * q;
            float s = szC[j];
            cnt += (s > my0) || (s == my0 && j < r0);
            cnt += ((s > my1) || (s == my1 && j < r1)) << 16;
        }
        cnt = ibfly(cnt);
        if (lane == 0) {
            int c0 = cnt & 0xffff, c1 = cnt >> 16;
            if (c0 < 300) {
                int io = sIDXp[0][r0];
                sIDXp[1][c0] = io;
                sHSo[io] = shvO[io] * sigm(my0);
                atomicOr(&sSELp[1][io >> 5], 1u << (io & 31));
            }
            if (c1 < 300) {
                int io = sIDXp[0][r1];
                sIDXp[1][c1] = io;
                sHSo[io] = shvO[io] * sigm(my1);
                atomicOr(&sSELp[1][io >> 5], 1u << (io & 31));
            }
        }
    }
    __syncthreads();
    // hop1: P = SEL2 ∩ CP[j1] ∩ ..., early exit
    unsigned P[16];
    int inew = 0, pc = 0;
    float su_ = 0.f;
    if (t < 300) {
        inew = sIDXp[1][t];
#pragma unroll
        for (int w = 0; w < 16; ++w) P[w] = sSELp[1][w];
        bool alive = true;
        for (int w2 = 0; w2 < 16 && alive; ++w2) {
            unsigned nb = sSELp[0][w2] & ~sCP[inew * MS + w2];
            while (nb) {
                int b = __ffs((int)nb) - 1;
                nb &= nb - 1;
                const unsigned* cj = sCP + (w2 * 32 + b) * MS;
                unsigned orr = 0;
#pragma unroll
                for (int w = 0; w < 16; ++w) {
                    P[w] &= cj[w];
                    orr |= P[w];
                }
                if (!orr) { alive = false; break; }
            }
        }
#pragma unroll
        for (int w = 0; w < 16; ++w) pc += __popc(P[w]);
        if (pc > 0) atomicOr(&sFlag, 1);
        float rs = (float)(300 - pc);
        su_ = sHSo[inew] * Wd.p[1][t] / rs;
    }
    __syncthreads();
    if (t < 300) {
#pragma unroll
        for (int w = 0; w < 16; ++w) sCP[inew * MS + w] = P[w];
        srsO[inew] = (float)(300 - pc);
        svC[t] = su_;
        svO[inew] = su_;
    } else if (t < 512) {
        svC[t] = 0.f;
    }
    __syncthreads();
    if (sFlag == 0) {
        // ---- scalar fast path: layers 1-3 graphs are complete ----
        if (t < 64) {
            float p = 0.f;
#pragma unroll
            for (int j = 0; j < 8; ++j) p += svC[t * 8 + j];
            p = fbfly(p);
            if (t == 0) {
                float h2 = fmaxf(p + bd.p[1][0], 0.f);
                float z2 = fmaxf(h2 * Wp.p[2][0] + bp.p[2][0], 0.f);
                sS[0] = h2;
                sS[1] = h2 * sigm(z2);
            }
        }
        __syncthreads();
        float HS2 = sS[1];
        if (t < 512) s2C[t] = (t < 200) ? HS2 * Wd.p[2][t] / 200.f : 0.f;
        __syncthreads();
        if (t < 64) {
            float p = 0.f;
#pragma unroll
            for (int j = 0; j < 8; ++j) p += s2C[t * 8 + j];
            p = fbfly(p);
            if (t == 0) {
                float h3 = fmaxf(p + bd.p[2][0], 0.f);
                float z3 = fmaxf(h3 * Wp.p[3][0] + bp.p[3][0], 0.f);
                sS[2] = h3;
                sS[3] = h3 * sigm(z3);
            }
        }
        __syncthreads();
        float HS3 = sS[3];
        if (t < 512) s2C[t] = (t < 100) ? HS3 * Wd.p[3][t] / 100.f : 0.f;
        __syncthreads();
        if (t < 64) {
            float p = 0.f;
#pragma unroll
            for (int j = 0; j < 8; ++j) p += s2C[t * 8 + j];
            p = fbfly(p);
            if (t == 0) sS[4] = fmaxf(p + bd.p[3][0], 0.f);
        }
        __syncthreads();
        if (t < 300) out[900 + t] = sS[0];
        else if (t < 500) out[1200 + (t - 300)] = sS[2];
        else if (t < 600) out[1400 + (t - 500)] = sS[4];
        return;
    }
    // ---- general fallback (correct; not expected to execute) ----
    const int kks[3] = {300, 200, 100};
    const int kns[3] = {200, 100, 0};
    const int offs[3] = {900, 1200, 1400};
    for (int l = 1; l <= 3; ++l) {
        const int kk = kks[l - 1], knext = kns[l - 1], off = offs[l - 1];
        const int cur = l & 1, nxt = cur ^ 1;
        if (t < 64) {
            float p = 0.f;
#pragma unroll
            for (int j = 0; j < 8; ++j) p += svC[t * 8 + j];
            p = fbfly(p);
            if (t == 0) stotS = p;
        }
        __syncthreads();
        int i_ = 0;
        if (t < kk) {
            i_ = sIDXp[cur][t];
            float corr = pwalk16(sCP + i_ * MS, svO);
            float hv = fmaxf(stotS - corr + bd.p[l][0], 0.f);
            out[off + t] = hv;
            shvO[i_] = hv;
            float s2 = hv / srsO[i_];
            s2C[t] = s2;
            s2O[i_] = s2;
        } else if (t < 512) {
            s2C[t] = 0.f;
        }
        if (l == 3) break;
        __syncthreads();
        if (t < 64) {
            float p = 0.f;
#pragma unroll
            for (int j = 0; j < 8; ++j) p += s2C[t * 8 + j];
            p = fbfly(p);
            if (t == 0) stotS = p;
        }
        if (t < 16) sSELp[nxt][t] = 0u;
        __syncthreads();
        float z_ = -1.f;
        if (t < kk) {
            float c2 = pwalk16(sCP + i_ * MS, s2O);
            z_ = fmaxf((stotS - c2) * Wp.p[l + 1][0] + bp.p[l + 1][0], 0.f);
        }
        if (t < 512) szC[t] = (t < kk) ? z_ : -1.f;
        __syncthreads();
        for (int r = wid; r < kk; r += 16) {
            float my = szC[r];
            int cnt = wrank(szC, my, r, lane);
            if (lane == 0 && cnt < knext) {
                int io = sIDXp[cur][r];
                sIDXp[nxt][cnt] = io;
                sHSo[io] = shvO[io] * sigm(my);
                atomicOr(&sSELp[nxt][io >> 5], 1u << (io & 31));
            }
        }
        __syncthreads();
        unsigned Q[16];
        int in2 = 0, pc2 = 0;
        float su2_ = 0.f;
        if (t < knext) {
            in2 = sIDXp[nxt][t];
#pragma unroll
            for (int w = 0; w < 16; ++w) Q[w] = sSELp[nxt][w];
            bool alive = true;
            for (int w2 = 0; w2 < 16 && alive; ++w2) {
                unsigned nb = sSELp[cur][w2] & ~sCP[in2 * MS + w2];
                while (nb) {
                    int b = __ffs((int)nb) - 1;
                    nb &= nb - 1;
                    const unsigned* cj = sCP + (w2 * 32 + b) * MS;
                    unsigned orr = 0;
#pragma unroll
                    for (int w = 0; w < 16; ++w) {
                        Q[w] &= cj[w];
                        orr |= Q[w];
                    }
                    if (!orr) { alive = false; break; }
                }
            }
#pragma unroll
            for (int w = 0; w < 16; ++w) pc2 += __popc(Q[w]);
            float rs = (float)(knext - pc2);
            su2_ = sHSo[in2] * Wd.p[l + 1][t] / rs;
        }
        __syncthreads();
        if (t < knext) {
#pragma unroll
            for (int w = 0; w < 16; ++w) sCP[in2 * MS + w] = Q[w];
            srsO[in2] = (float)(knext - pc2);
            svC[t] = su2_;
            svO[in2] = su2_;
        } else if (t < 512) {
            svC[t] = 0.f;
        }
        __syncthreads();
    }
}

extern "C" void kernel_launch(void* const* d_in, const int* in_sizes, int n_in,
                              void* d_out, int out_size, void* d_ws, size_t ws_size,
                              hipStream_t stream) {
    const float* g = (const float*)d_in[0];
    const float* h = (const float*)d_in[1];
    const float* W_top = (const float*)d_in[2];
    const float* b_top = (const float*)d_in[3];
    P4 Wp, bp, Wd, bd;
    for (int i = 0; i < 4; ++i) {
        Wp.p[i] = (const float*)d_in[4 + 4 * i];
        bp.p[i] = (const float*)d_in[5 + 4 * i];
        Wd.p[i] = (const float*)d_in[6 + 4 * i];
        bd.p[i] = (const float*)d_in[7 + 4 * i];
    }
    float* out = (float*)d_out;

    unsigned* wsu = (unsigned*)d_ws;
    float* V = (float*)(wsu + 0);
    float* SHg = (float*)(wsu + 512);
    float* Zg = (float*)(wsu + 1024);
    int* IDXA = (int*)(wsu + 1536);
    float* HSo = (float*)(wsu + 2048);
    unsigned* CPP = wsu + 2560;
    unsigned* MA = wsu + 10560;

    k_dot<<<500, 1024, 0, stream>>>(h, W_top, g, V, MA);
    k_row<<<125, 256, 0, stream>>>(MA, V, b_top, nullptr, SHg, out, 0);
    k_row<<<125, 256, 0, stream>>>(MA, SHg, Wp.p[0], bp.p[0], Zg, nullptr, 1);
    k_rh<<<125, 256, 0, stream>>>(MA, SHg, Zg, IDXA, HSo, CPP);
    k_fin<<<1, 1024, 0, stream>>>(IDXA, CPP, HSo, Wp, bp, Wd, bd, out);
}